// Round 3
// baseline (536.077 us; speedup 1.0000x reference)
//
#include <hip/hip_runtime.h>
#include <hip/hip_bf16.h>

#define DMODEL 1024
#define DH 64
#define BB 4
#define SS 2048
#define NROW (BB * SS)   // 8192

// ---------------- fused QKV projection ----------------
// C(8192 x 192) = emb(8192 x 1024) @ [Wq|Wk|Wv](1024 x 192) + [bq|bk|bv]
#define PBM 16
#define PBK 32

__global__ __launch_bounds__(256) void qkv_proj_kernel(
    const float* __restrict__ emb,
    const float* __restrict__ Wq, const float* __restrict__ bq,
    const float* __restrict__ Wk, const float* __restrict__ bk,
    const float* __restrict__ Wv, const float* __restrict__ bv,
    float* __restrict__ Q, float* __restrict__ K, float* __restrict__ V)
{
    __shared__ float Es[PBM][PBK + 1];       // 16 x 33
    __shared__ float Ws[PBK][192 + 1];       // 32 x 193

    const int tid  = threadIdx.x;            // 256
    const int row0 = blockIdx.x * PBM;
    const int ty   = tid >> 5;               // 0..7  -> rows ty*2, ty*2+1
    const int tx   = tid & 31;               // 0..31 -> cols tx + 32*j

    float acc[2][6];
    #pragma unroll
    for (int i = 0; i < 2; ++i)
        #pragma unroll
        for (int j = 0; j < 6; ++j) acc[i][j] = 0.f;

    for (int k0 = 0; k0 < DMODEL; k0 += PBK) {
        // E tile: 16x32 = 128 float4, threads 0..127
        if (tid < 128) {
            int r  = tid >> 3;
            int c4 = tid & 7;
            const float4 e = *reinterpret_cast<const float4*>(
                emb + (size_t)(row0 + r) * DMODEL + k0 + c4 * 4);
            Es[r][c4*4+0] = e.x; Es[r][c4*4+1] = e.y;
            Es[r][c4*4+2] = e.z; Es[r][c4*4+3] = e.w;
        }
        // W tile: 32 x 192 = 1536 float4, 6 per thread
        #pragma unroll
        for (int j = 0; j < 6; ++j) {
            int idx = tid + j * 256;
            int kk  = idx / 48;           // 0..31
            int c   = (idx % 48) * 4;     // 0..188
            const float* src; int cc;
            if (c < 64)       { src = Wq; cc = c;       }
            else if (c < 128) { src = Wk; cc = c - 64;  }
            else              { src = Wv; cc = c - 128; }
            const float4 w = *reinterpret_cast<const float4*>(
                src + (size_t)(k0 + kk) * DH + cc);
            Ws[kk][c+0] = w.x; Ws[kk][c+1] = w.y;
            Ws[kk][c+2] = w.z; Ws[kk][c+3] = w.w;
        }
        __syncthreads();
        #pragma unroll 8
        for (int kk = 0; kk < PBK; ++kk) {
            float a0 = Es[ty*2+0][kk];
            float a1 = Es[ty*2+1][kk];
            #pragma unroll
            for (int j = 0; j < 6; ++j) {
                float b = Ws[kk][tx + 32*j];
                acc[0][j] += a0 * b;
                acc[1][j] += a1 * b;
            }
        }
        __syncthreads();
    }

    #pragma unroll
    for (int i = 0; i < 2; ++i) {
        int r = row0 + ty*2 + i;
        #pragma unroll
        for (int j = 0; j < 6; ++j) {
            int c = tx + 32*j;
            if (c < 64)       Q[(size_t)r*DH + c]         = acc[i][j] + bq[c];
            else if (c < 128) K[(size_t)r*DH + (c - 64)]  = acc[i][j] + bk[c - 64];
            else              V[(size_t)r*DH + (c - 128)] = acc[i][j] + bv[c - 128];
        }
    }
}

// ---------------- causal flash attention (fp32) ----------------
#define QBLK 64
#define KBLK 64

__global__ __launch_bounds__(512) void attn_kernel(
    const float* __restrict__ Q, const float* __restrict__ K,
    const float* __restrict__ V, float* __restrict__ out)
{
    __shared__ float Qs[QBLK][DH + 1];
    __shared__ float Ks[KBLK][DH + 1];
    __shared__ float Vs[KBLK][DH + 1];
    __shared__ float Ss[QBLK][KBLK + 1];
    __shared__ float mrow[QBLK], lrow[QBLK], arow[QBLK];

    const int tid = threadIdx.x;           // 512
    const int qt  = blockIdx.x;
    const int b   = blockIdx.y;
    const int q0  = qt * QBLK;
    const float* Qb = Q + (size_t)b * SS * DH;
    const float* Kb = K + (size_t)b * SS * DH;
    const float* Vb = V + (size_t)b * SS * DH;

    // load Q tile: 64x64 = 1024 float4, 2 per thread
    #pragma unroll
    for (int j = 0; j < 2; ++j) {
        int idx = tid + j * 512;
        int r = idx >> 4, c4 = idx & 15;
        const float4 v = *reinterpret_cast<const float4*>(
            Qb + (size_t)(q0 + r) * DH + c4 * 4);
        Qs[r][c4*4+0] = v.x; Qs[r][c4*4+1] = v.y;
        Qs[r][c4*4+2] = v.z; Qs[r][c4*4+3] = v.w;
    }
    if (tid < QBLK) { mrow[tid] = -1e30f; lrow[tid] = 0.f; }
    __syncthreads();   // Q tile + softmax state visible to all

    const int ty = tid >> 4;    // 0..31 -> rows ty*2, ty*2+1
    const int tx = tid & 15;    // cols tx*4 .. tx*4+3
    float acc[2][4];
    #pragma unroll
    for (int i = 0; i < 2; ++i)
        #pragma unroll
        for (int j = 0; j < 4; ++j) acc[i][j] = 0.f;

    for (int kt = 0; kt <= qt; ++kt) {
        const int k0 = kt * KBLK;
        #pragma unroll
        for (int j = 0; j < 2; ++j) {
            int idx = tid + j * 512;
            int r = idx >> 4, c4 = idx & 15;
            const float4 kv = *reinterpret_cast<const float4*>(
                Kb + (size_t)(k0 + r) * DH + c4 * 4);
            Ks[r][c4*4+0] = kv.x; Ks[r][c4*4+1] = kv.y;
            Ks[r][c4*4+2] = kv.z; Ks[r][c4*4+3] = kv.w;
            const float4 vv = *reinterpret_cast<const float4*>(
                Vb + (size_t)(k0 + r) * DH + c4 * 4);
            Vs[r][c4*4+0] = vv.x; Vs[r][c4*4+1] = vv.y;
            Vs[r][c4*4+2] = vv.z; Vs[r][c4*4+3] = vv.w;
        }
        __syncthreads();   // K/V tile ready

        // S = Q Ktile^T
        float s[2][4];
        #pragma unroll
        for (int i = 0; i < 2; ++i)
            #pragma unroll
            for (int j = 0; j < 4; ++j) s[i][j] = 0.f;
        #pragma unroll 4
        for (int d = 0; d < DH; ++d) {
            float a0 = Qs[ty*2+0][d];
            float a1 = Qs[ty*2+1][d];
            #pragma unroll
            for (int j = 0; j < 4; ++j) {
                float bb = Ks[tx*4+j][d];
                s[0][j] += a0 * bb;
                s[1][j] += a1 * bb;
            }
        }
        // scale + causal mask, write to LDS
        #pragma unroll
        for (int i = 0; i < 2; ++i) {
            int qg = q0 + ty*2 + i;
            #pragma unroll
            for (int j = 0; j < 4; ++j) {
                int kg = k0 + tx*4 + j;
                float v = s[i][j] * 0.125f;
                Ss[ty*2+i][tx*4+j] = (kg > qg) ? -1e30f : v;
            }
        }
        __syncthreads();   // Ss complete

        // online softmax per row (threads 0..63)
        if (tid < QBLK) {
            const int r = tid;
            float m = mrow[r];
            float mx = m;
            #pragma unroll 8
            for (int c = 0; c < KBLK; ++c) mx = fmaxf(mx, Ss[r][c]);
            float alpha = __expf(m - mx);
            float sum = 0.f;
            #pragma unroll 8
            for (int c = 0; c < KBLK; ++c) {
                float p = __expf(Ss[r][c] - mx);
                Ss[r][c] = p;
                sum += p;
            }
            lrow[r] = lrow[r] * alpha + sum;
            mrow[r] = mx;
            arow[r] = alpha;
        }
        __syncthreads();   // P + alpha ready

        // rescale + PV
        float al0 = arow[ty*2+0];
        float al1 = arow[ty*2+1];
        #pragma unroll
        for (int j = 0; j < 4; ++j) { acc[0][j] *= al0; acc[1][j] *= al1; }
        #pragma unroll 4
        for (int kk = 0; kk < KBLK; ++kk) {
            float p0 = Ss[ty*2+0][kk];
            float p1 = Ss[ty*2+1][kk];
            #pragma unroll
            for (int j = 0; j < 4; ++j) {
                float vv = Vs[kk][tx*4+j];
                acc[0][j] += p0 * vv;
                acc[1][j] += p1 * vv;
            }
        }
        __syncthreads();   // done reading Ks/Vs/Ss before next tile overwrites
    }

    float* ob = out + (size_t)b * SS * DH;
    float inv0 = 1.f / lrow[ty*2+0];
    float inv1 = 1.f / lrow[ty*2+1];
    #pragma unroll
    for (int j = 0; j < 4; ++j) {
        ob[(size_t)(q0 + ty*2 + 0) * DH + tx*4 + j] = acc[0][j] * inv0;
        ob[(size_t)(q0 + ty*2 + 1) * DH + tx*4 + j] = acc[1][j] * inv1;
    }
}

extern "C" void kernel_launch(void* const* d_in, const int* in_sizes, int n_in,
                              void* d_out, int out_size, void* d_ws, size_t ws_size,
                              hipStream_t stream) {
    const float* emb = (const float*)d_in[0];
    const float* Wq  = (const float*)d_in[1];
    const float* bq  = (const float*)d_in[2];
    const float* Wk  = (const float*)d_in[3];
    const float* bk  = (const float*)d_in[4];
    const float* Wv  = (const float*)d_in[5];
    const float* bv  = (const float*)d_in[6];
    float* out = (float*)d_out;

    float* ws = (float*)d_ws;
    float* Q = ws;
    float* K = ws + (size_t)NROW * DH;
    float* V = ws + (size_t)2 * NROW * DH;

    hipLaunchKernelGGL(qkv_proj_kernel, dim3(NROW / PBM), dim3(256), 0, stream,
                       emb, Wq, bq, Wk, bk, Wv, bv, Q, K, V);
    hipLaunchKernelGGL(attn_kernel, dim3(SS / QBLK, BB), dim3(512), 0, stream,
                       Q, K, V, out);
}

// Round 5
// 131.529 us; speedup vs baseline: 4.0757x; 4.0757x over previous
//
#include <hip/hip_runtime.h>
#include <hip/hip_bf16.h>

#define DMODEL 1024
#define DH 64
#define BB 4
#define SS 2048
#define NROW (BB * SS)   // 8192

typedef __attribute__((ext_vector_type(8))) short bf16x8;
typedef __attribute__((ext_vector_type(4))) float f32x4;

__device__ __forceinline__ unsigned short f2bf(float f) {
    __hip_bfloat16 h = __float2bfloat16(f);
    return __builtin_bit_cast(unsigned short, h);
}

// ---------------- prep: Wt[192][1024] bf16 = [Wq|Wk|Wv]^T ----------------
__global__ __launch_bounds__(256) void prep_wt_kernel(
    const float* __restrict__ Wq, const float* __restrict__ Wk,
    const float* __restrict__ Wv, unsigned short* __restrict__ Wt)
{
    int idx = blockIdx.x * 256 + threadIdx.x;      // 0 .. 196607
    int m   = idx >> 16;                           // 0..2
    int rem = idx & 65535;
    int k   = rem >> 6;
    int n   = rem & 63;
    const float* W = (m == 0) ? Wq : (m == 1) ? Wk : Wv;
    float v = W[(size_t)k * DH + n];               // coalesced read
    Wt[(size_t)(m * 64 + n) * DMODEL + k] = f2bf(v);
}

// ---------------- QKV projection via MFMA ----------------
// per block: 16 rows x 192 cols; 4 waves, wave w -> cols 48w..48w+47 (3 tiles)
__global__ __launch_bounds__(256) void qkv_proj_mfma(
    const float* __restrict__ emb, const unsigned short* __restrict__ Wt,
    const float* __restrict__ bq, const float* __restrict__ bk,
    const float* __restrict__ bv,
    unsigned short* __restrict__ Q, unsigned short* __restrict__ K,
    unsigned short* __restrict__ V)
{
    __shared__ unsigned short A_lds[16][72];

    const int tid  = threadIdx.x;
    const int lane = tid & 63;
    const int w    = tid >> 6;          // wave 0..3
    const int c    = lane & 15;
    const int g    = lane >> 4;         // 0..3
    const int row0 = blockIdx.x * 16;

    f32x4 acc[3];
    #pragma unroll
    for (int t = 0; t < 3; ++t) acc[t] = (f32x4){0.f, 0.f, 0.f, 0.f};

    const int sr  = tid >> 4;           // staging row 0..15
    const int sc4 = tid & 15;           // staging float4 col

    for (int k0 = 0; k0 < DMODEL; k0 += 64) {
        // stage A tile 16x64 fp32 -> bf16 LDS (1 float4/thread)
        {
            const float4 e = *reinterpret_cast<const float4*>(
                emb + (size_t)(row0 + sr) * DMODEL + k0 + sc4 * 4);
            uint2 pk;
            pk.x = (unsigned)f2bf(e.x) | ((unsigned)f2bf(e.y) << 16);
            pk.y = (unsigned)f2bf(e.z) | ((unsigned)f2bf(e.w) << 16);
            *reinterpret_cast<uint2*>(&A_lds[sr][sc4 * 4]) = pk;
        }
        __syncthreads();

        bf16x8 a[2];
        #pragma unroll
        for (int kp = 0; kp < 2; ++kp)
            a[kp] = __builtin_bit_cast(bf16x8,
                *reinterpret_cast<const uint4*>(&A_lds[c][32 * kp + 8 * g]));

        #pragma unroll
        for (int t = 0; t < 3; ++t) {
            const int ncol = 48 * w + 16 * t + c;
            #pragma unroll
            for (int kp = 0; kp < 2; ++kp) {
                bf16x8 bfr = __builtin_bit_cast(bf16x8,
                    *reinterpret_cast<const uint4*>(
                        &Wt[(size_t)ncol * DMODEL + k0 + 32 * kp + 8 * g]));
                acc[t] = __builtin_amdgcn_mfma_f32_16x16x32_bf16(a[kp], bfr, acc[t], 0, 0, 0);
            }
        }
        __syncthreads();
    }

    // epilogue: bias (+ 1/8 scale folded into Q), store bf16
    #pragma unroll
    for (int t = 0; t < 3; ++t) {
        const int col = 48 * w + 16 * t + c;
        const int m   = col >> 6;
        const int lc  = col & 63;
        const float* bias = (m == 0) ? bq : (m == 1) ? bk : bv;
        unsigned short* O = (m == 0) ? Q : (m == 1) ? K : V;
        const float bs    = bias[lc];
        const float scale = (m == 0) ? 0.125f : 1.0f;
        #pragma unroll
        for (int i = 0; i < 4; ++i) {
            const int r = row0 + 4 * g + i;
            O[(size_t)r * DH + lc] = f2bf((acc[t][i] + bs) * scale);
        }
    }
}

// ---------------- causal flash attention via MFMA ----------------
// block: (q-tile of 64, batch); 4 waves, wave w -> q rows 16w..16w+15
__global__ __launch_bounds__(256) void attn_mfma(
    const unsigned short* __restrict__ Q, const unsigned short* __restrict__ K,
    const unsigned short* __restrict__ V, float* __restrict__ out)
{
    __shared__ unsigned short Ks[64][72];      // [kv][d]
    __shared__ unsigned short Vt[64][72];      // [d][kv]  (transposed)
    __shared__ unsigned short Ps[4][16][72];   // per-wave P tile [qrow][kv]

    const int tid  = threadIdx.x;
    const int lane = tid & 63;
    const int w    = tid >> 6;
    const int c    = lane & 15;
    const int g    = lane >> 4;
    const int qt   = blockIdx.x;
    const int b    = blockIdx.y;
    const int q0   = qt * 64;

    const unsigned short* Qb = Q + (size_t)b * SS * DH;
    const unsigned short* Kb = K + (size_t)b * SS * DH;
    const unsigned short* Vb = V + (size_t)b * SS * DH;

    // Q fragments, register resident (scale 1/8 already folded in)
    bf16x8 qa[2];
    #pragma unroll
    for (int kp = 0; kp < 2; ++kp)
        qa[kp] = __builtin_bit_cast(bf16x8,
            *reinterpret_cast<const uint4*>(
                &Qb[(size_t)(q0 + 16 * w + c) * DH + 32 * kp + 8 * g]));

    f32x4 o[4];
    #pragma unroll
    for (int t = 0; t < 4; ++t) o[t] = (f32x4){0.f, 0.f, 0.f, 0.f};
    float m_i[4] = {-1e30f, -1e30f, -1e30f, -1e30f};
    float l_i[4] = {0.f, 0.f, 0.f, 0.f};

    for (int kt = 0; kt <= qt; ++kt) {
        const int kb0 = kt * 64;
        __syncthreads();   // prior tile's LDS reads done
        // stage K (row-major) and V (transposed), 2 x 16B per thread each
        #pragma unroll
        for (int j = 0; j < 2; ++j) {
            const int idx = tid + 256 * j;
            const int kv  = idx >> 3;
            const int d0  = (idx & 7) * 8;
            *reinterpret_cast<uint4*>(&Ks[kv][d0]) =
                *reinterpret_cast<const uint4*>(&Kb[(size_t)(kb0 + kv) * DH + d0]);
            const uint4 vv =
                *reinterpret_cast<const uint4*>(&Vb[(size_t)(kb0 + kv) * DH + d0]);
            const unsigned wd[4] = {vv.x, vv.y, vv.z, vv.w};
            #pragma unroll
            for (int e = 0; e < 8; ++e)
                Vt[d0 + e][kv] = (unsigned short)(wd[e >> 1] >> (16 * (e & 1)));
        }
        __syncthreads();

        // S = Q Ktile^T  (4 col-tiles x 2 k-steps)
        f32x4 s[4];
        #pragma unroll
        for (int t = 0; t < 4; ++t) s[t] = (f32x4){0.f, 0.f, 0.f, 0.f};
        #pragma unroll
        for (int t = 0; t < 4; ++t)
            #pragma unroll
            for (int kp = 0; kp < 2; ++kp) {
                bf16x8 kf = __builtin_bit_cast(bf16x8,
                    *reinterpret_cast<const uint4*>(&Ks[16 * t + c][32 * kp + 8 * g]));
                s[t] = __builtin_amdgcn_mfma_f32_16x16x32_bf16(qa[kp], kf, s[t], 0, 0, 0);
            }

        // causal mask (only the diagonal tile needs it)
        if (kt == qt) {
            #pragma unroll
            for (int t = 0; t < 4; ++t)
                #pragma unroll
                for (int i = 0; i < 4; ++i)
                    if (16 * t + c > 16 * w + 4 * g + i) s[t][i] = -1e30f;
        }

        // wave-parallel online softmax; quarter-wave owns q-rows 4g..4g+3 (i)
        float al[4];
        #pragma unroll
        for (int i = 0; i < 4; ++i) {
            float v = fmaxf(fmaxf(s[0][i], s[1][i]), fmaxf(s[2][i], s[3][i]));
            v = fmaxf(v, __shfl_xor(v, 1));
            v = fmaxf(v, __shfl_xor(v, 2));
            v = fmaxf(v, __shfl_xor(v, 4));
            v = fmaxf(v, __shfl_xor(v, 8));
            const float mn = fmaxf(m_i[i], v);
            al[i] = __expf(m_i[i] - mn);
            m_i[i] = mn;
        }
        #pragma unroll
        for (int t = 0; t < 4; ++t)
            #pragma unroll
            for (int i = 0; i < 4; ++i)
                s[t][i] = __expf(s[t][i] - m_i[i]);
        #pragma unroll
        for (int i = 0; i < 4; ++i) {
            float r = s[0][i] + s[1][i] + s[2][i] + s[3][i];
            r += __shfl_xor(r, 1);
            r += __shfl_xor(r, 2);
            r += __shfl_xor(r, 4);
            r += __shfl_xor(r, 8);
            l_i[i] = l_i[i] * al[i] + r;
        }

        // P -> per-wave LDS (reshape to A-fragment layout)
        #pragma unroll
        for (int t = 0; t < 4; ++t)
            #pragma unroll
            for (int i = 0; i < 4; ++i)
                Ps[w][4 * g + i][16 * t + c] = f2bf(s[t][i]);

        // rescale O
        #pragma unroll
        for (int t = 0; t < 4; ++t)
            #pragma unroll
            for (int i = 0; i < 4; ++i)
                o[t][i] *= al[i];

        // O += P Vtile   (A = P from LDS, B = V from transposed LDS)
        #pragma unroll
        for (int kp = 0; kp < 2; ++kp) {
            bf16x8 pa = __builtin_bit_cast(bf16x8,
                *reinterpret_cast<const uint4*>(&Ps[w][c][32 * kp + 8 * g]));
            #pragma unroll
            for (int t = 0; t < 4; ++t) {
                bf16x8 vf = __builtin_bit_cast(bf16x8,
                    *reinterpret_cast<const uint4*>(&Vt[16 * t + c][32 * kp + 8 * g]));
                o[t] = __builtin_amdgcn_mfma_f32_16x16x32_bf16(pa, vf, o[t], 0, 0, 0);
            }
        }
    }

    // epilogue
    float inv[4];
    #pragma unroll
    for (int i = 0; i < 4; ++i) inv[i] = 1.f / l_i[i];
    float* ob = out + ((size_t)b * SS + q0 + 16 * w) * DH;
    #pragma unroll
    for (int t = 0; t < 4; ++t)
        #pragma unroll
        for (int i = 0; i < 4; ++i)
            ob[(size_t)(4 * g + i) * DH + 16 * t + c] = o[t][i] * inv[i];
}

extern "C" void kernel_launch(void* const* d_in, const int* in_sizes, int n_in,
                              void* d_out, int out_size, void* d_ws, size_t ws_size,
                              hipStream_t stream) {
    const float* emb = (const float*)d_in[0];
    const float* Wq  = (const float*)d_in[1];
    const float* bq  = (const float*)d_in[2];
    const float* Wk  = (const float*)d_in[3];
    const float* bk  = (const float*)d_in[4];
    const float* Wv  = (const float*)d_in[5];
    const float* bv  = (const float*)d_in[6];
    float* out = (float*)d_out;

    unsigned short* Qw = (unsigned short*)d_ws;
    unsigned short* Kw = Qw + (size_t)NROW * DH;
    unsigned short* Vw = Kw + (size_t)NROW * DH;
    unsigned short* Wt = Vw + (size_t)NROW * DH;   // 192*1024 bf16

    hipLaunchKernelGGL(prep_wt_kernel, dim3(768), dim3(256), 0, stream,
                       Wq, Wk, Wv, Wt);
    hipLaunchKernelGGL(qkv_proj_mfma, dim3(NROW / 16), dim3(256), 0, stream,
                       emb, Wt, bq, bk, bv, Qw, Kw, Vw);
    hipLaunchKernelGGL(attn_mfma, dim3(SS / 64, BB), dim3(256), 0, stream,
                       Qw, Kw, Vw, out);
}

// Round 6
// 73.204 us; speedup vs baseline: 7.3230x; 1.7967x over previous
//
#include <hip/hip_runtime.h>
#include <hip/hip_bf16.h>

#define DMODEL 1024
#define DH 64
#define BB 4
#define SS 2048
#define NROW (BB * SS)   // 8192
#define NS 4             // kv-splits per q-tile

typedef __attribute__((ext_vector_type(8))) short bf16x8;
typedef __attribute__((ext_vector_type(4))) float f32x4;

__device__ __forceinline__ unsigned short f2bf(float f) {
    __hip_bfloat16 h = __float2bfloat16(f);
    return __builtin_bit_cast(unsigned short, h);
}

// ---------------- prep: Wt[192][1024] bf16 = [Wq|Wk|Wv]^T ----------------
__global__ __launch_bounds__(256) void prep_wt_kernel(
    const float* __restrict__ Wq, const float* __restrict__ Wk,
    const float* __restrict__ Wv, unsigned short* __restrict__ Wt)
{
    int idx = blockIdx.x * 256 + threadIdx.x;      // 0 .. 196607
    int m   = idx >> 16;                           // 0..2
    int rem = idx & 65535;
    int k   = rem >> 6;
    int n   = rem & 63;
    const float* W = (m == 0) ? Wq : (m == 1) ? Wk : Wv;
    float v = W[(size_t)k * DH + n];               // coalesced read
    Wt[(size_t)(m * 64 + n) * DMODEL + k] = f2bf(v);
}

// ---------------- QKV projection via MFMA ----------------
// per block: 16 rows x 192 cols; 4 waves, wave w -> cols 48w..48w+47 (3 tiles)
__global__ __launch_bounds__(256) void qkv_proj_mfma(
    const float* __restrict__ emb, const unsigned short* __restrict__ Wt,
    const float* __restrict__ bq, const float* __restrict__ bk,
    const float* __restrict__ bv,
    unsigned short* __restrict__ Q, unsigned short* __restrict__ K,
    unsigned short* __restrict__ V)
{
    __shared__ unsigned short A_lds[16][72];

    const int tid  = threadIdx.x;
    const int lane = tid & 63;
    const int w    = tid >> 6;          // wave 0..3
    const int c    = lane & 15;
    const int g    = lane >> 4;         // 0..3
    const int row0 = blockIdx.x * 16;

    f32x4 acc[3];
    #pragma unroll
    for (int t = 0; t < 3; ++t) acc[t] = (f32x4){0.f, 0.f, 0.f, 0.f};

    const int sr  = tid >> 4;           // staging row 0..15
    const int sc4 = tid & 15;           // staging float4 col

    for (int k0 = 0; k0 < DMODEL; k0 += 64) {
        // stage A tile 16x64 fp32 -> bf16 LDS (1 float4/thread)
        {
            const float4 e = *reinterpret_cast<const float4*>(
                emb + (size_t)(row0 + sr) * DMODEL + k0 + sc4 * 4);
            uint2 pk;
            pk.x = (unsigned)f2bf(e.x) | ((unsigned)f2bf(e.y) << 16);
            pk.y = (unsigned)f2bf(e.z) | ((unsigned)f2bf(e.w) << 16);
            *reinterpret_cast<uint2*>(&A_lds[sr][sc4 * 4]) = pk;
        }
        __syncthreads();

        bf16x8 a[2];
        #pragma unroll
        for (int kp = 0; kp < 2; ++kp)
            a[kp] = __builtin_bit_cast(bf16x8,
                *reinterpret_cast<const uint4*>(&A_lds[c][32 * kp + 8 * g]));

        #pragma unroll
        for (int t = 0; t < 3; ++t) {
            const int ncol = 48 * w + 16 * t + c;
            #pragma unroll
            for (int kp = 0; kp < 2; ++kp) {
                bf16x8 bfr = __builtin_bit_cast(bf16x8,
                    *reinterpret_cast<const uint4*>(
                        &Wt[(size_t)ncol * DMODEL + k0 + 32 * kp + 8 * g]));
                acc[t] = __builtin_amdgcn_mfma_f32_16x16x32_bf16(a[kp], bfr, acc[t], 0, 0, 0);
            }
        }
        __syncthreads();
    }

    // epilogue: bias (+ 1/8 scale folded into Q), store bf16
    #pragma unroll
    for (int t = 0; t < 3; ++t) {
        const int col = 48 * w + 16 * t + c;
        const int m   = col >> 6;
        const int lc  = col & 63;
        const float* bias = (m == 0) ? bq : (m == 1) ? bk : bv;
        unsigned short* O = (m == 0) ? Q : (m == 1) ? K : V;
        const float bs    = bias[lc];
        const float scale = (m == 0) ? 0.125f : 1.0f;
        #pragma unroll
        for (int i = 0; i < 4; ++i) {
            const int r = row0 + 4 * g + i;
            O[(size_t)r * DH + lc] = f2bf((acc[t][i] + bs) * scale);
        }
    }
}

// ---------------- causal flash attention via MFMA, KV-split ----------------
// grid (qt, b, s): block handles q-tile qt of batch b, k-tiles [kt0, kt1)
// writes UNNORMALIZED partials: Opart[s][row][d], mpart[s][row], lpart[s][row]
__global__ __launch_bounds__(256) void attn_mfma_split(
    const unsigned short* __restrict__ Q, const unsigned short* __restrict__ K,
    const unsigned short* __restrict__ V,
    float* __restrict__ Opart, float* __restrict__ mpart,
    float* __restrict__ lpart)
{
    __shared__ unsigned short Ks[64][72];      // [kv][d]
    __shared__ unsigned short Vt[64][72];      // [d][kv]  (transposed)
    __shared__ unsigned short Ps[4][16][72];   // per-wave P tile [qrow][kv]

    const int tid  = threadIdx.x;
    const int lane = tid & 63;
    const int w    = tid >> 6;
    const int c    = lane & 15;
    const int g    = lane >> 4;
    const int qt   = blockIdx.x;
    const int b    = blockIdx.y;
    const int sp   = blockIdx.z;
    const int q0   = qt * 64;

    const int ntile = qt + 1;
    const int kt0 = (ntile * sp) / NS;
    const int kt1 = (ntile * (sp + 1)) / NS;

    const unsigned short* Qb = Q + (size_t)b * SS * DH;
    const unsigned short* Kb = K + (size_t)b * SS * DH;
    const unsigned short* Vb = V + (size_t)b * SS * DH;

    // Q fragments, register resident (scale 1/8 already folded in)
    bf16x8 qa[2];
    #pragma unroll
    for (int kp = 0; kp < 2; ++kp)
        qa[kp] = __builtin_bit_cast(bf16x8,
            *reinterpret_cast<const uint4*>(
                &Qb[(size_t)(q0 + 16 * w + c) * DH + 32 * kp + 8 * g]));

    f32x4 o[4];
    #pragma unroll
    for (int t = 0; t < 4; ++t) o[t] = (f32x4){0.f, 0.f, 0.f, 0.f};
    float m_i[4] = {-1e30f, -1e30f, -1e30f, -1e30f};
    float l_i[4] = {0.f, 0.f, 0.f, 0.f};

    for (int kt = kt0; kt < kt1; ++kt) {
        const int kb0 = kt * 64;
        __syncthreads();   // prior tile's LDS reads done
        // stage K (row-major) and V (transposed), 2 x 16B per thread each
        #pragma unroll
        for (int j = 0; j < 2; ++j) {
            const int idx = tid + 256 * j;
            const int kv  = idx >> 3;
            const int d0  = (idx & 7) * 8;
            *reinterpret_cast<uint4*>(&Ks[kv][d0]) =
                *reinterpret_cast<const uint4*>(&Kb[(size_t)(kb0 + kv) * DH + d0]);
            const uint4 vv =
                *reinterpret_cast<const uint4*>(&Vb[(size_t)(kb0 + kv) * DH + d0]);
            const unsigned wd[4] = {vv.x, vv.y, vv.z, vv.w};
            #pragma unroll
            for (int e = 0; e < 8; ++e)
                Vt[d0 + e][kv] = (unsigned short)(wd[e >> 1] >> (16 * (e & 1)));
        }
        __syncthreads();

        // S = Q Ktile^T  (4 col-tiles x 2 k-steps)
        f32x4 s[4];
        #pragma unroll
        for (int t = 0; t < 4; ++t) s[t] = (f32x4){0.f, 0.f, 0.f, 0.f};
        #pragma unroll
        for (int t = 0; t < 4; ++t)
            #pragma unroll
            for (int kp = 0; kp < 2; ++kp) {
                bf16x8 kf = __builtin_bit_cast(bf16x8,
                    *reinterpret_cast<const uint4*>(&Ks[16 * t + c][32 * kp + 8 * g]));
                s[t] = __builtin_amdgcn_mfma_f32_16x16x32_bf16(qa[kp], kf, s[t], 0, 0, 0);
            }

        // causal mask (only the diagonal tile needs it)
        if (kt == qt) {
            #pragma unroll
            for (int t = 0; t < 4; ++t)
                #pragma unroll
                for (int i = 0; i < 4; ++i)
                    if (16 * t + c > 16 * w + 4 * g + i) s[t][i] = -1e30f;
        }

        // wave-parallel online softmax; quarter-wave owns q-rows 4g..4g+3 (i)
        float al[4];
        #pragma unroll
        for (int i = 0; i < 4; ++i) {
            float v = fmaxf(fmaxf(s[0][i], s[1][i]), fmaxf(s[2][i], s[3][i]));
            v = fmaxf(v, __shfl_xor(v, 1));
            v = fmaxf(v, __shfl_xor(v, 2));
            v = fmaxf(v, __shfl_xor(v, 4));
            v = fmaxf(v, __shfl_xor(v, 8));
            const float mn = fmaxf(m_i[i], v);
            al[i] = __expf(m_i[i] - mn);
            m_i[i] = mn;
        }
        #pragma unroll
        for (int t = 0; t < 4; ++t)
            #pragma unroll
            for (int i = 0; i < 4; ++i)
                s[t][i] = __expf(s[t][i] - m_i[i]);
        #pragma unroll
        for (int i = 0; i < 4; ++i) {
            float r = s[0][i] + s[1][i] + s[2][i] + s[3][i];
            r += __shfl_xor(r, 1);
            r += __shfl_xor(r, 2);
            r += __shfl_xor(r, 4);
            r += __shfl_xor(r, 8);
            l_i[i] = l_i[i] * al[i] + r;
        }

        // P -> per-wave LDS (reshape to A-fragment layout)
        #pragma unroll
        for (int t = 0; t < 4; ++t)
            #pragma unroll
            for (int i = 0; i < 4; ++i)
                Ps[w][4 * g + i][16 * t + c] = f2bf(s[t][i]);

        // rescale O
        #pragma unroll
        for (int t = 0; t < 4; ++t)
            #pragma unroll
            for (int i = 0; i < 4; ++i)
                o[t][i] *= al[i];

        // O += P Vtile   (A = P from LDS, B = V from transposed LDS)
        #pragma unroll
        for (int kp = 0; kp < 2; ++kp) {
            bf16x8 pa = __builtin_bit_cast(bf16x8,
                *reinterpret_cast<const uint4*>(&Ps[w][c][32 * kp + 8 * g]));
            #pragma unroll
            for (int t = 0; t < 4; ++t) {
                bf16x8 vf = __builtin_bit_cast(bf16x8,
                    *reinterpret_cast<const uint4*>(&Vt[16 * t + c][32 * kp + 8 * g]));
                o[t] = __builtin_amdgcn_mfma_f32_16x16x32_bf16(pa, vf, o[t], 0, 0, 0);
            }
        }
    }

    // epilogue: unnormalized partials
    const int rowbase = b * SS + q0 + 16 * w;
    #pragma unroll
    for (int t = 0; t < 4; ++t)
        #pragma unroll
        for (int i = 0; i < 4; ++i)
            Opart[((size_t)sp * NROW + rowbase + 4 * g + i) * DH + 16 * t + c] = o[t][i];
    if (c == 0) {
        #pragma unroll
        for (int i = 0; i < 4; ++i) {
            mpart[(size_t)sp * NROW + rowbase + 4 * g + i] = m_i[i];
            lpart[(size_t)sp * NROW + rowbase + 4 * g + i] = l_i[i];
        }
    }
}

// ---------------- combine partials ----------------
__global__ __launch_bounds__(256) void attn_combine(
    const float* __restrict__ Opart, const float* __restrict__ mpart,
    const float* __restrict__ lpart, float* __restrict__ out)
{
    const int idx = blockIdx.x * 256 + threadIdx.x;   // row*16 + d4
    const int row = idx >> 4;
    const int d4  = (idx & 15) * 4;

    float m[NS];
    float M = -1e30f;
    #pragma unroll
    for (int s = 0; s < NS; ++s) {
        m[s] = mpart[(size_t)s * NROW + row];
        M = fmaxf(M, m[s]);
    }
    float L = 0.f;
    float4 acc = {0.f, 0.f, 0.f, 0.f};
    #pragma unroll
    for (int s = 0; s < NS; ++s) {
        const float wgt = __expf(m[s] - M);
        L += wgt * lpart[(size_t)s * NROW + row];
        const float4 p = *reinterpret_cast<const float4*>(
            &Opart[((size_t)s * NROW + row) * DH + d4]);
        acc.x += wgt * p.x; acc.y += wgt * p.y;
        acc.z += wgt * p.z; acc.w += wgt * p.w;
    }
    const float inv = 1.f / L;
    float4 r = {acc.x * inv, acc.y * inv, acc.z * inv, acc.w * inv};
    *reinterpret_cast<float4*>(&out[(size_t)row * DH + d4]) = r;
}

extern "C" void kernel_launch(void* const* d_in, const int* in_sizes, int n_in,
                              void* d_out, int out_size, void* d_ws, size_t ws_size,
                              hipStream_t stream) {
    const float* emb = (const float*)d_in[0];
    const float* Wq  = (const float*)d_in[1];
    const float* bq  = (const float*)d_in[2];
    const float* Wk  = (const float*)d_in[3];
    const float* bk  = (const float*)d_in[4];
    const float* Wv  = (const float*)d_in[5];
    const float* bv  = (const float*)d_in[6];
    float* out = (float*)d_out;

    unsigned short* Qw = (unsigned short*)d_ws;
    unsigned short* Kw = Qw + (size_t)NROW * DH;
    unsigned short* Vw = Kw + (size_t)NROW * DH;
    unsigned short* Wt = Vw + (size_t)NROW * DH;          // 192*1024 bf16
    float* Opart = (float*)(Wt + (size_t)192 * DMODEL);   // [NS][NROW][DH] f32
    float* mpart = Opart + (size_t)NS * NROW * DH;        // [NS][NROW]
    float* lpart = mpart + (size_t)NS * NROW;             // [NS][NROW]

    hipLaunchKernelGGL(prep_wt_kernel, dim3(768), dim3(256), 0, stream,
                       Wq, Wk, Wv, Wt);
    hipLaunchKernelGGL(qkv_proj_mfma, dim3(NROW / 16), dim3(256), 0, stream,
                       emb, Wt, bq, bk, bv, Qw, Kw, Vw);
    hipLaunchKernelGGL(attn_mfma_split, dim3(SS / 64, BB, NS), dim3(256), 0, stream,
                       Qw, Kw, Vw, Opart, mpart, lpart);
    hipLaunchKernelGGL(attn_combine, dim3(NROW * 16 / 256), dim3(256), 0, stream,
                       Opart, mpart, lpart, out);
}